// Round 6
// baseline (237.971 us; speedup 1.0000x reference)
//
#include <hip/hip_runtime.h>

#define NN 50
#define D 64

__device__ __forceinline__ float wave_sum64(float x) {
#pragma unroll
  for (int off = 32; off > 0; off >>= 1)
    x += __shfl_xor(x, off, 64);
  return x;
}

__device__ __forceinline__ float readlane_f(float v, int l) {
  return __uint_as_float(__builtin_amdgcn_readlane(__float_as_uint(v), l));
}

// One pairing step of the simultaneous reduction: lanes with (lane&bit)==0
// keep vector a and receive a's other half; lanes with bit set keep b.
__device__ __forceinline__ float pairred(float a, float b, int bit, int lane) {
  const float keep = (lane & bit) ? b : a;
  const float send = (lane & bit) ? a : b;
  return keep + __shfl_xor(send, bit, 64);
}

// Dot of 16 rows (lane=dim) against Wn (lane=dim) in 17 shuffles total.
// Result: lane l holds dot(v[l&15], Wn).
__device__ __forceinline__ float tree16(const float (&v)[16], float Wn, int lane) {
  float w[8];
#pragma unroll
  for (int k = 0; k < 8; ++k)
    w[k] = pairred(v[2 * k] * Wn, v[2 * k + 1] * Wn, 1, lane);
  float x[4];
#pragma unroll
  for (int k = 0; k < 4; ++k)
    x[k] = pairred(w[2 * k], w[2 * k + 1], 2, lane);
  float y0 = pairred(x[0], x[1], 4, lane);
  float y1 = pairred(x[2], x[3], 4, lane);
  float z  = pairred(y0, y1, 8, lane);
  z += __shfl_xor(z, 16, 64);
  z += __shfl_xor(z, 32, 64);
  return z;
}

__device__ __forceinline__ void load16(float (&buf)[16],
                                       const int* __restrict__ adjb,
                                       const float* __restrict__ ent_tab,
                                       int g, int lane) {
#pragma unroll
  for (int i = 0; i < 16; ++i) {
    int t = adjb[g * 16 + i];              // wave-uniform -> s_load
    t = t < 0 ? 0 : t;
    buf[i] = ent_tab[(size_t)t * D + lane];  // coalesced 256B row
  }
}

// Score+exp for one 16-group, accumulate weighted rows into na and the
// per-slot exp partial into dsum (summed across the 16-slot later).
__device__ __forceinline__ void proc16(const float (&v)[16], float Wn, float base,
                                       float& na, float& dsum, int lane) {
  float s = tree16(v, Wn, lane) + base;
  s = s > 0.f ? s : 0.2f * s;              // leaky_relu(0.2)
  // fixed-max softmax: scores are leaky_relu of ~unit-variance dots,
  // bounded well below 8 -> exp(s-8) can't overflow, denom can't underflow.
  const float ex = __expf(s - 8.0f);
  dsum += ex;                              // lane slot (16-periodic duplicates)
#pragma unroll
  for (int i = 0; i < 16; ++i)
    na = fmaf(readlane_f(ex, i), v[i], na);
}

__global__ __launch_bounds__(256, 4) void kgat_fwd(
    const int* __restrict__ user_idx, const int* __restrict__ item_idx,
    const int* __restrict__ adj,
    const float* __restrict__ user_tab, const float* __restrict__ item_tab,
    const float* __restrict__ ent_tab,
    const float* __restrict__ attn_W, const float* __restrict__ attn_b,
    const float* __restrict__ W1, const float* __restrict__ b1,
    const float* __restrict__ W2, const float* __restrict__ b2,
    const float* __restrict__ cW, const float* __restrict__ cb,
    const float* __restrict__ oW, const float* __restrict__ ob,
    float* __restrict__ out, int B)
{
  const int lane = threadIdx.x & 63;
  const int wv   = threadIdx.x >> 6;
  const int b    = blockIdx.x * 4 + wv;
  if (b >= B) return;

  // Hoist long-latency loads whose results are needed late.
  const float user = user_tab[(long)user_idx[b] * D + lane];
  const float item = item_tab[(long)item_idx[b] * D + lane];
  const float Wn   = attn_W[D + lane];
  const float base = wave_sum64(item * attn_W[lane]) + attn_b[0];  // uniform

  const int* adjb = adj + b * NN;

  // ---- attention: 3 groups of 16 + trailing 2, double-buffered ----
  float na = 0.f, dsum = 0.f;
  float VA[16], VB[16];

  load16(VA, adjb, ent_tab, 0, lane);
  load16(VB, adjb, ent_tab, 1, lane);
  proc16(VA, Wn, base, na, dsum, lane);            // neighbors 0-15
  load16(VA, adjb, ent_tab, 2, lane);
  proc16(VB, Wn, base, na, dsum, lane);            // neighbors 16-31
  {                                                 // rows 48,49 into VB[0..1]
    int t0 = adjb[48]; t0 = t0 < 0 ? 0 : t0;
    int t1 = adjb[49]; t1 = t1 < 0 ? 0 : t1;
    VB[0] = ent_tab[(size_t)t0 * D + lane];
    VB[1] = ent_tab[(size_t)t1 * D + lane];
  }
  proc16(VA, Wn, base, na, dsum, lane);            // neighbors 32-47

  // denominator from the three 16-groups: sum the 16 slots
  dsum += __shfl_xor(dsum, 1, 64);
  dsum += __shfl_xor(dsum, 2, 64);
  dsum += __shfl_xor(dsum, 4, 64);
  dsum += __shfl_xor(dsum, 8, 64);

  // trailing neighbors 48,49: one pairing + 5 closing butterflies
  {
    float z = pairred(VB[0] * Wn, VB[1] * Wn, 1, lane);
    z += __shfl_xor(z, 2, 64);
    z += __shfl_xor(z, 4, 64);
    z += __shfl_xor(z, 8, 64);
    z += __shfl_xor(z, 16, 64);
    z += __shfl_xor(z, 32, 64);
    float s = z + base;
    s = s > 0.f ? s : 0.2f * s;
    const float ex  = __expf(s - 8.0f);
    const float e48 = readlane_f(ex, 0);
    const float e49 = readlane_f(ex, 1);
    dsum += e48 + e49;
    na = fmaf(e48, VB[0], na);
    na = fmaf(e49, VB[1], na);
  }
  na /= dsum;

  // ---- h = relu(na @ W1 + b1): lane owns column, 4-way accumulators ----
  float h0 = b1[lane], h1 = 0.f, h2 = 0.f, h3 = 0.f;
#pragma unroll
  for (int d = 0; d < D; d += 4) {
    h0 = fmaf(readlane_f(na, d + 0), W1[(d + 0) * D + lane], h0);
    h1 = fmaf(readlane_f(na, d + 1), W1[(d + 1) * D + lane], h1);
    h2 = fmaf(readlane_f(na, d + 2), W1[(d + 2) * D + lane], h2);
    h3 = fmaf(readlane_f(na, d + 3), W1[(d + 3) * D + lane], h3);
  }
  const float h = fmaxf((h0 + h1) + (h2 + h3), 0.f);

  // ---- r = h @ W2 + b2 ----
  float r0 = b2[lane], r1 = 0.f, r2 = 0.f, r3 = 0.f;
#pragma unroll
  for (int d = 0; d < D; d += 4) {
    r0 = fmaf(readlane_f(h, d + 0), W2[(d + 0) * D + lane], r0);
    r1 = fmaf(readlane_f(h, d + 1), W2[(d + 1) * D + lane], r1);
    r2 = fmaf(readlane_f(h, d + 2), W2[(d + 2) * D + lane], r2);
    r3 = fmaf(readlane_f(h, d + 3), W2[(d + 3) * D + lane], r3);
  }
  const float r = (r0 + r1) + (r2 + r3);

  // ---- f = relu([item, r] @ cW + cb) ----
  float f0 = cb[lane], f1 = 0.f, f2 = 0.f, f3 = 0.f;
#pragma unroll
  for (int k = 0; k < D; k += 4) {
    f0 = fmaf(readlane_f(item, k + 0), cW[(k + 0) * D + lane], f0);
    f1 = fmaf(readlane_f(item, k + 1), cW[(k + 1) * D + lane], f1);
    f2 = fmaf(readlane_f(item, k + 2), cW[(k + 2) * D + lane], f2);
    f3 = fmaf(readlane_f(item, k + 3), cW[(k + 3) * D + lane], f3);
  }
#pragma unroll
  for (int k = 0; k < D; k += 4) {
    f0 = fmaf(readlane_f(r, k + 0), cW[(D + k + 0) * D + lane], f0);
    f1 = fmaf(readlane_f(r, k + 1), cW[(D + k + 1) * D + lane], f1);
    f2 = fmaf(readlane_f(r, k + 2), cW[(D + k + 2) * D + lane], f2);
    f3 = fmaf(readlane_f(r, k + 3), cW[(D + k + 3) * D + lane], f3);
  }
  const float f = fmaxf((f0 + f1) + (f2 + f3), 0.f);

  // ---- score = dot([user, f], oW) + ob ----
  const float sc = wave_sum64(fmaf(user, oW[lane], f * oW[D + lane]));
  if (lane == 0) out[b] = sc + ob[0];
}

extern "C" void kernel_launch(void* const* d_in, const int* in_sizes, int n_in,
                              void* d_out, int out_size, void* d_ws, size_t ws_size,
                              hipStream_t stream) {
  const int*   user_idx = (const int*)d_in[0];
  const int*   item_idx = (const int*)d_in[1];
  const int*   adj      = (const int*)d_in[2];
  const float* user_tab = (const float*)d_in[3];
  const float* item_tab = (const float*)d_in[4];
  const float* ent_tab  = (const float*)d_in[5];
  const float* attn_W   = (const float*)d_in[6];
  const float* attn_b   = (const float*)d_in[7];
  const float* W1       = (const float*)d_in[8];
  const float* b1       = (const float*)d_in[9];
  const float* W2       = (const float*)d_in[10];
  const float* b2       = (const float*)d_in[11];
  const float* cW       = (const float*)d_in[12];
  const float* cb       = (const float*)d_in[13];
  const float* oW       = (const float*)d_in[14];
  const float* ob       = (const float*)d_in[15];
  float* out = (float*)d_out;

  const int B = in_sizes[0];
  const int blocks = (B + 3) / 4;   // 4 waves (1 element each) per block
  kgat_fwd<<<blocks, 256, 0, stream>>>(user_idx, item_idx, adj,
                                       user_tab, item_tab, ent_tab,
                                       attn_W, attn_b, W1, b1, W2, b2,
                                       cW, cb, oW, ob, out, B);
}